// Round 2
// baseline (540.043 us; speedup 1.0000x reference)
//
#include <hip/hip_runtime.h>

// Problem geometry (compile-time constants from the reference).
static constexpr int XD = 400;
static constexpr int YD = 400;
static constexpr int ZD = 8;
static constexpr int CD = 64;                         // channels per cell
static constexpr int NCELLS = XD * YD * ZD;           // 1,280,000 cells
static constexpr long long CELL_F4 = CD / 4;          // 16 float4 per cell row

// 1) winner[cell] = -1. (Harness poisons ws with 0xAA each call — that is
//    negative as int, but init explicitly; cost is ~5 MB, negligible.)
__global__ void init_winner_kernel(int* __restrict__ w, int n) {
    int i = blockIdx.x * blockDim.x + threadIdx.x;
    if (i < n) w[i] = -1;
}

// 2) last-write-wins resolution: highest update index claims the cell.
//    (XLA .at[].set applies updates in order; last duplicate wins.)
__global__ void winner_kernel(const int* __restrict__ idx,
                              int* __restrict__ w, int n) {
    int i = blockIdx.x * blockDim.x + threadIdx.x;
    if (i >= n) return;
    int ix = idx[3 * i + 0];
    int iy = idx[3 * i + 1];
    int iz = idx[3 * i + 2];
    int cell = (ix * YD + iy) * ZD + iz;
    atomicMax(&w[cell], i);
}

// 3) single merged output pass: every out float4 written exactly once.
//    16 threads own one cell row (64 floats). Source address selected
//    branchlessly: winning pixels row, else the voxel row.
__global__ void merge_kernel(const float4* __restrict__ vox,
                             const float4* __restrict__ pixels,
                             const int* __restrict__ w,
                             float4* __restrict__ out) {
    long long t = (long long)blockIdx.x * blockDim.x + threadIdx.x;
    int cell = (int)(t >> 4);      // 16 threads per cell
    int c    = (int)(t & 15);      // float4 slot within the row
    if (cell >= NCELLS) return;
    int win = w[cell];             // broadcast within each 16-thread group (L2-hot)
    const float4* src = (win >= 0) ? (pixels + (long long)win * CELL_F4)
                                   : (vox    + (long long)cell * CELL_F4);
    out[(long long)cell * CELL_F4 + c] = src[c];
}

extern "C" void kernel_launch(void* const* d_in, const int* in_sizes, int n_in,
                              void* d_out, int out_size, void* d_ws, size_t ws_size,
                              hipStream_t stream) {
    const float4* voxel  = (const float4*)d_in[0];
    const int*    sidx   = (const int*)d_in[1];
    const float4* pixels = (const float4*)d_in[2];
    float4*       out4   = (float4*)d_out;
    int*          winner = (int*)d_ws;               // 1.28M ints = 5.12 MB

    const int N = in_sizes[1] / 3;                   // 134,400 updates

    // 1) init winner array
    {
        int threads = 256;
        int blocks = (NCELLS + threads - 1) / threads;
        init_winner_kernel<<<blocks, threads, 0, stream>>>(winner, NCELLS);
    }
    // 2) resolve duplicate cells (last index wins)
    {
        int threads = 256;
        int blocks = (N + threads - 1) / threads;
        winner_kernel<<<blocks, threads, 0, stream>>>(sidx, winner, N);
    }
    // 3) merged copy+scatter: one write per output element (HBM-bound bulk)
    {
        int threads = 256;
        long long total = (long long)NCELLS * 16;
        int blocks = (int)((total + threads - 1) / threads);   // 80,000 blocks
        merge_kernel<<<blocks, threads, 0, stream>>>(voxel, pixels, winner, out4);
    }
}